// Round 6
// baseline (2655.766 us; speedup 1.0000x reference)
//
#include <hip/hip_runtime.h>

#define NPERM_C 250000
#define P_C     4000000          // slots = NPERM * 16
#define G_C     4096
#define NB1     1954             // ceil(P_C / 2048) big scan
#define NB2     123              // ceil(NPERM_C / 2048) pool scan

typedef __attribute__((ext_vector_type(8))) short bf16x8;
typedef __attribute__((ext_vector_type(4))) float f32x4;

static __device__ __forceinline__ unsigned short f2bf(float f) {
    unsigned u = __float_as_uint(f);
    unsigned r = (u + 0x7fffu + ((u >> 16) & 1u)) >> 16;   // RNE
    return (unsigned short)r;
}
static __device__ __forceinline__ float bf2f(unsigned short s) {
    return __uint_as_float(((unsigned)s) << 16);
}

// ---------------------------------------------------------------------------
// fragment-ordered split-bf16 weight tables
// ---------------------------------------------------------------------------
__global__ void repack_bpk(const float* __restrict__ w, unsigned short* __restrict__ bpk) {
    int o = blockIdx.x * 256 + threadIdx.x;          // 131072 total
    int j = o & 7, lane = (o >> 3) & 63, h = (o >> 9) & 1;
    int nt = (o >> 10) & 3, ks = (o >> 12) & 1, l = o >> 13;
    int b = ks * 32 + (lane >> 4) * 8 + j;
    int c = nt * 16 + (lane & 15);
    float wv = w[(b * 64 + c) * 16 + l];
    unsigned short hb = f2bf(wv);
    bpk[o] = (h == 0) ? hb : f2bf(wv - bf2f(hb));
}

__global__ void repack_wlpk(const float* __restrict__ wl, unsigned short* __restrict__ wpk) {
    int o = blockIdx.x * 256 + threadIdx.x;          // 8192 total
    int j = o & 7, lane = (o >> 3) & 63, h = (o >> 9) & 1;
    int nt = (o >> 10) & 3, ks = o >> 12;
    int k = ks * 32 + (lane >> 4) * 8 + j;
    int c2 = nt * 16 + (lane & 15);
    float wv = wl[c2 * 64 + k];
    unsigned short hb = f2bf(wv);
    wpk[o] = (h == 0) ? hb : f2bf(wv - bf2f(hb));
}

// ---------------------------------------------------------------------------
// pool reference histogram: poolCnt[c] = #times perm row c is pooled.
// ---------------------------------------------------------------------------
__global__ __launch_bounds__(256) void pool_hist(const int* __restrict__ pcol,
                                                 int* __restrict__ poolCnt) {
    int i = blockIdx.x * 256 + threadIdx.x;
    if (i < NPERM_C) atomicAdd(&poolCnt[pcol[i]], 1);
}

// active-row compaction scan (flag = cnt!=0), deterministic.
__global__ __launch_bounds__(256) void pool_scan_local(const int* __restrict__ poolCnt,
                                                       int* __restrict__ poolRank,
                                                       int* __restrict__ bsum2) {
    __shared__ int ts[256];
    int b = blockIdx.x, t = threadIdx.x;
    int base = b * 2048 + t * 8;
    int v[8]; int s = 0;
#pragma unroll
    for (int i = 0; i < 8; ++i) {
        int idx = base + i;
        v[i] = (idx < NPERM_C) ? (poolCnt[idx] != 0) : 0;
        s += v[i];
    }
    ts[t] = s;
    __syncthreads();
    for (int ofs = 1; ofs < 256; ofs <<= 1) {
        int xv = (t >= ofs) ? ts[t - ofs] : 0;
        __syncthreads();
        ts[t] += xv;
        __syncthreads();
    }
    int run = ts[t] - s;
    if (t == 255) bsum2[b] = ts[255];
#pragma unroll
    for (int i = 0; i < 8; ++i) {
        int idx = base + i;
        if (idx < NPERM_C) poolRank[idx] = run;
        run += v[i];
    }
}

__global__ void pool_scan_top(int* __restrict__ bsum2) {
    __shared__ int ts[256];
    int t = threadIdx.x;
    int v = (t < NB2) ? bsum2[t] : 0;
    ts[t] = v;
    __syncthreads();
    for (int ofs = 1; ofs < 256; ofs <<= 1) {
        int xv = (t >= ofs) ? ts[t - ofs] : 0;
        __syncthreads();
        ts[t] += xv;
        __syncthreads();
    }
    if (t < NB2) bsum2[t] = ts[t] - v;
}

__global__ __launch_bounds__(256) void pool_scan_add(const int* __restrict__ poolCnt,
                                                     int* __restrict__ poolRank,
                                                     const int* __restrict__ bsum2,
                                                     int* __restrict__ act,
                                                     int* __restrict__ nActB) {
    int b = blockIdx.x, t = threadIdx.x;
    int add = bsum2[b];
    int base = b * 2048 + t * 8;
#pragma unroll
    for (int i = 0; i < 8; ++i) {
        int idx = base + i;
        if (idx < NPERM_C) {
            int flag = poolCnt[idx] != 0;
            int o = poolRank[idx] + add;
            poolRank[idx] = o;
            if (flag) act[o] = idx;
            if (idx == NPERM_C - 1) nActB[0] = o + flag;
        }
    }
}

// ---------------------------------------------------------------------------
// slot histogram over ACTIVE rows only.
// ---------------------------------------------------------------------------
__global__ __launch_bounds__(256) void hist(const int* __restrict__ r1,
                                            const int* __restrict__ r2,
                                            const int* __restrict__ poolCnt,
                                            int* __restrict__ cnt) {
    int i = blockIdx.x * 256 + threadIdx.x;
    int r;
    if (i < P_C)            r = r1[i];
    else if (i < 2 * P_C)   r = r2[i - P_C];
    else return;
    if (poolCnt[r >> 4] != 0) atomicAdd(&cnt[r], 1);
}

// big exclusive scan over 4M slot counts.
__global__ __launch_bounds__(256) void scan_local(const int* __restrict__ cnt,
                                                  int* __restrict__ off,
                                                  int* __restrict__ bsum) {
    __shared__ int ts[256];
    int b = blockIdx.x, t = threadIdx.x;
    int base = b * 2048 + t * 8;
    int v[8]; int s = 0;
#pragma unroll
    for (int i = 0; i < 8; ++i) {
        int idx = base + i;
        v[i] = (idx < P_C) ? cnt[idx] : 0;
        s += v[i];
    }
    ts[t] = s;
    __syncthreads();
    for (int ofs = 1; ofs < 256; ofs <<= 1) {
        int xv = (t >= ofs) ? ts[t - ofs] : 0;
        __syncthreads();
        ts[t] += xv;
        __syncthreads();
    }
    int run = ts[t] - s;
    if (t == 255) bsum[b] = ts[255];
#pragma unroll
    for (int i = 0; i < 8; ++i) {
        int idx = base + i;
        if (idx < P_C) off[idx] = run;
        run += v[i];
    }
}

__global__ void scan_top(int* __restrict__ bsum) {
    __shared__ int ts[256];
    int t = threadIdx.x;
    int base = t * 8;
    int v[8]; int s = 0;
#pragma unroll
    for (int i = 0; i < 8; ++i) {
        int idx = base + i;
        v[i] = (idx < NB1) ? bsum[idx] : 0;
        s += v[i];
    }
    ts[t] = s;
    __syncthreads();
    for (int ofs = 1; ofs < 256; ofs <<= 1) {
        int xv = (t >= ofs) ? ts[t - ofs] : 0;
        __syncthreads();
        ts[t] += xv;
        __syncthreads();
    }
    int run = ts[t] - s;
#pragma unroll
    for (int i = 0; i < 8; ++i) {
        int idx = base + i;
        if (idx < NB1) bsum[idx] = run;
        run += v[i];
    }
}

__global__ __launch_bounds__(256) void scan_add(int* __restrict__ off,
                                                const int* __restrict__ bsum,
                                                int* __restrict__ cur) {
    int b = blockIdx.x, t = threadIdx.x;
    int add = bsum[b];
    int base = b * 2048 + t * 8;
#pragma unroll
    for (int i = 0; i < 8; ++i) {
        int idx = base + i;
        if (idx < P_C) {
            int o = off[idx] + add;
            if (idx == P_C - 1) off[P_C] = o + cur[idx];  // cur still holds count
            off[idx] = o;
            cur[idx] = o;
        }
    }
}

// ---------------------------------------------------------------------------
// scatter active entries to sorted position.
// ---------------------------------------------------------------------------
__global__ __launch_bounds__(256) void scat(
        const int* __restrict__ r1, const int* __restrict__ c1, const float* __restrict__ v1,
        const int* __restrict__ r2, const int* __restrict__ c2, const float* __restrict__ v2,
        const int* __restrict__ poolCnt,
        int* __restrict__ cur, uint2* __restrict__ suv) {
    int i = blockIdx.x * 256 + threadIdx.x;
    int row; unsigned key; float val;
    if (i < P_C)          { row = r1[i]; key = (unsigned)c1[i]; val = v1[i]; }
    else if (i < 2 * P_C) { int j = i - P_C; row = r2[j]; key = (unsigned)c2[j] | 0x100000u; val = v2[j]; }
    else return;
    if (poolCnt[row >> 4] == 0) return;
    int pos = atomicAdd(&cur[row], 1);
    suv[pos] = make_uint2(key, __float_as_uint(val));
}

// ---------------------------------------------------------------------------
// Entry-parallel CSR gather with LDS segmented reduction.
// Block = 8 compact rows. Stage act + 17 slot offsets per row into LDS,
// zero a fp32 accumulator accS[8][16][64], then each 16-lane group walks
// its row's contiguous sorted entry range (2 groups/row, stride 2):
// broadcast suv load -> float4 feature gather -> 4x ds_add_f32.
// Epilogue: fp32 -> split-bf16 planes (coalesced), degree-gate slots.
// ---------------------------------------------------------------------------
__global__ __launch_bounds__(256) void gather_nfeat(
        const uint2* __restrict__ suv, const int* __restrict__ pOff,
        const float* __restrict__ x, const float* __restrict__ efeat,
        const float* __restrict__ degs, const int* __restrict__ act,
        const int* __restrict__ nActB,
        unsigned short* __restrict__ nfH, unsigned short* __restrict__ nfL,
        float* __restrict__ degD, int row0, int rows) {
    __shared__ float accS[8192];     // [8 rows][16 slots][64 d]
    __shared__ int   offS[8][17];
    __shared__ int   arowS[8];
    __shared__ float degS[8][4];
    int nAct = nActB[0];
    int t = threadIdx.x;
    int cr0 = row0 + blockIdx.x * 8;
    int rend = row0 + rows; if (rend > nAct) rend = nAct;
    if (cr0 >= rend) return;

    if (t < 8) arowS[t] = (cr0 + t < rend) ? act[cr0 + t] : -1;
    __syncthreads();
    if (t < 136) {
        int r = t / 17, j = t - r * 17;
        int ar = arowS[r];
        offS[r][j] = (ar >= 0) ? pOff[ar * 16 + j] : 0;
    }
#pragma unroll
    for (int i = 0; i < 32; ++i) accS[t + i * 256] = 0.f;
    if (t < 32) degS[t >> 2][t & 3] = 0.f;
    __syncthreads();

    {
        int w = t >> 6;               // wave 0..3
        int g = (t >> 4) & 3;         // 16-lane group in wave
        int t16 = t & 15;
        int r = w * 2 + (g >> 1);     // row 0..7
        int par = g & 1;
        int e0 = offS[r][0], e1 = offS[r][16];
        int s = 0;
        for (int e = e0 + par; e < e1; e += 2) {
            while (s < 15 && e >= offS[r][s + 1]) ++s;
            uint2 kv = suv[e];
            unsigned k = kv.x;
            float v = __uint_as_float(kv.y);
            const float* f = (k & 0x100000u) ? efeat : x;
            float4 fv = *reinterpret_cast<const float4*>(
                f + (size_t)(k & 0xFFFFFu) * 64 + t16 * 4);
            float* dst = &accS[(r * 16 + s) * 64 + t16 * 4];
            atomicAdd(dst + 0, v * fv.x);
            atomicAdd(dst + 1, v * fv.y);
            atomicAdd(dst + 2, v * fv.z);
            atomicAdd(dst + 3, v * fv.w);
            if (t16 == 0 && !(k & 0x100000u)) {
                if (s == 0 || s == 5 || s == 10 || s == 15)
                    atomicAdd(&degS[r][s / 5], v * degs[k & 0xFFFFFu]);
            }
        }
    }
    __syncthreads();

    size_t nfbase = (size_t)(cr0 - row0) * 1024;
#pragma unroll
    for (int it = 0; it < 8; ++it) {
        if (cr0 + it >= rend) break;     // row `it` (1024 floats = 256 thr x 4)
        int flat = it * 1024 + t * 4;
        float4 a = *reinterpret_cast<const float4*>(&accS[flat]);
        ushort4 h4, l4;
        h4.x = f2bf(a.x); l4.x = f2bf(a.x - bf2f(h4.x));
        h4.y = f2bf(a.y); l4.y = f2bf(a.y - bf2f(h4.y));
        h4.z = f2bf(a.z); l4.z = f2bf(a.z - bf2f(h4.z));
        h4.w = f2bf(a.w); l4.w = f2bf(a.w - bf2f(h4.w));
        *reinterpret_cast<ushort4*>(nfH + nfbase + flat) = h4;
        *reinterpret_cast<ushort4*>(nfL + nfbase + flat) = l4;
    }
    if (t < 32) {
        int r2 = t >> 2;
        if (cr0 + r2 < rend)
            degD[(size_t)(cr0 + r2) * 4 + (t & 3)] = degS[r2][t & 3];
    }
}

// ---------------------------------------------------------------------------
// degree-gate MLP over compact rows [r0, min(r0+rows, nAct)).
// ---------------------------------------------------------------------------
__global__ __launch_bounds__(256) void dg_gemm(
        const float* __restrict__ degD,
        const float* __restrict__ W0, const float* __restrict__ b0,
        const float* __restrict__ W1, const float* __restrict__ b1,
        const int* __restrict__ nActB,
        float* __restrict__ dgb, int r0, int rows) {
    __shared__ float hidT[128][68];   // [h][r]
    __shared__ float w1T[128][68];    // [h][c]
    __shared__ float dloc[64][4];
    __shared__ float w0s[128][5];
    int nAct = nActB[0];
    int rend = r0 + rows; if (rend > nAct) rend = nAct;
    int t = threadIdx.x;
    int m0 = r0 + blockIdx.x * 64;
    if (m0 >= rend) return;

    {
        int r = t >> 2, j = t & 3;
        int gr = m0 + r; if (gr >= rend) gr = rend - 1;
        dloc[r][j] = degD[(size_t)gr * 4 + j];
    }
    if (t < 128) {
        w0s[t][0] = W0[t * 4 + 0]; w0s[t][1] = W0[t * 4 + 1];
        w0s[t][2] = W0[t * 4 + 2]; w0s[t][3] = W0[t * 4 + 3];
        w0s[t][4] = b0[t];
    }
    for (int s = 0; s < 32; ++s) {
        int idx = t + s * 256;
        w1T[idx & 127][idx >> 7] = W1[idx];
    }
    __syncthreads();
    for (int s = 0; s < 32; ++s) {
        int idx = t + s * 256;
        int h = idx & 127, r = idx >> 7;
        float v = w0s[h][4] + dloc[r][0] * w0s[h][0] + dloc[r][1] * w0s[h][1]
                            + dloc[r][2] * w0s[h][2] + dloc[r][3] * w0s[h][3];
        hidT[h][r] = fmaxf(v, 0.f);
    }
    __syncthreads();

    int tm = t >> 4, tn = t & 15;
    float acc[4][4] = {};
#pragma unroll 8
    for (int k = 0; k < 128; ++k) {
        float4 a = *reinterpret_cast<const float4*>(&hidT[k][tm * 4]);
        float4 b = *reinterpret_cast<const float4*>(&w1T[k][tn * 4]);
        acc[0][0] = fmaf(a.x, b.x, acc[0][0]); acc[0][1] = fmaf(a.x, b.y, acc[0][1]);
        acc[0][2] = fmaf(a.x, b.z, acc[0][2]); acc[0][3] = fmaf(a.x, b.w, acc[0][3]);
        acc[1][0] = fmaf(a.y, b.x, acc[1][0]); acc[1][1] = fmaf(a.y, b.y, acc[1][1]);
        acc[1][2] = fmaf(a.y, b.z, acc[1][2]); acc[1][3] = fmaf(a.y, b.w, acc[1][3]);
        acc[2][0] = fmaf(a.z, b.x, acc[2][0]); acc[2][1] = fmaf(a.z, b.y, acc[2][1]);
        acc[2][2] = fmaf(a.z, b.z, acc[2][2]); acc[2][3] = fmaf(a.z, b.w, acc[2][3]);
        acc[3][0] = fmaf(a.w, b.x, acc[3][0]); acc[3][1] = fmaf(a.w, b.y, acc[3][1]);
        acc[3][2] = fmaf(a.w, b.z, acc[3][2]); acc[3][3] = fmaf(a.w, b.w, acc[3][3]);
    }
    float bb[4] = {b1[tn * 4 + 0], b1[tn * 4 + 1], b1[tn * 4 + 2], b1[tn * 4 + 3]};
#pragma unroll
    for (int i = 0; i < 4; ++i) {
        int grow = m0 + tm * 4 + i;
        if (grow < rend) {
            float4 o = {acc[i][0] + bb[0], acc[i][1] + bb[1],
                        acc[i][2] + bb[2], acc[i][3] + bb[3]};
            *reinterpret_cast<float4*>(&dgb[(size_t)grow * 64 + tn * 4]) = o;
        }
    }
}

// ---------------------------------------------------------------------------
// MFMA einsum + epilogue (split-bf16, 3 products) over compact rows.
// ---------------------------------------------------------------------------
__global__ __launch_bounds__(256) void gemm_mfma(
        const unsigned short* __restrict__ nfH, const unsigned short* __restrict__ nfL,
        const unsigned short* __restrict__ Bpk, const unsigned short* __restrict__ Wlpk,
        const float* __restrict__ bias, const float* __restrict__ bl,
        const float* __restrict__ dgb, const int* __restrict__ nActB,
        float* __restrict__ outb, int r0, int rows) {
    __shared__ unsigned short Hh[128][72];
    __shared__ unsigned short Hl[128][72];
    int nAct = nActB[0];
    int rowsEff = rows; if (r0 + rowsEff > nAct) rowsEff = nAct - r0;
    int t = threadIdx.x, lane = t & 63, w = t >> 6;
    int m0 = blockIdx.x * 128;
    if (m0 >= rowsEff) return;
    int r16 = lane & 15, kg = lane >> 4;

    f32x4 acc[2][4];
#pragma unroll
    for (int i = 0; i < 2; ++i)
#pragma unroll
        for (int j = 0; j < 4; ++j) acc[i][j] = (f32x4){0.f, 0.f, 0.f, 0.f};

    for (int l = 0; l < 16; ++l) {
#pragma unroll
        for (int ks = 0; ks < 2; ++ks) {
            bf16x8 ah[2], al[2];
#pragma unroll
            for (int mt = 0; mt < 2; ++mt) {
                int lr = m0 + w * 32 + mt * 16 + r16;
                if (lr >= rowsEff) lr = rowsEff - 1;
                size_t off = ((size_t)lr * 16 + l) * 64 + ks * 32 + kg * 8;
                ah[mt] = *reinterpret_cast<const bf16x8*>(nfH + off);
                al[mt] = *reinterpret_cast<const bf16x8*>(nfL + off);
            }
#pragma unroll
            for (int nt = 0; nt < 4; ++nt) {
                const unsigned short* bb =
                    Bpk + (size_t)(((l * 2 + ks) * 4 + nt) * 2) * 512 + lane * 8;
                bf16x8 bh = *reinterpret_cast<const bf16x8*>(bb);
                bf16x8 blo = *reinterpret_cast<const bf16x8*>(bb + 512);
#pragma unroll
                for (int mt = 0; mt < 2; ++mt) {
                    acc[mt][nt] = __builtin_amdgcn_mfma_f32_16x16x32_bf16(ah[mt], bh,  acc[mt][nt], 0, 0, 0);
                    acc[mt][nt] = __builtin_amdgcn_mfma_f32_16x16x32_bf16(ah[mt], blo, acc[mt][nt], 0, 0, 0);
                    acc[mt][nt] = __builtin_amdgcn_mfma_f32_16x16x32_bf16(al[mt], bh,  acc[mt][nt], 0, 0, 0);
                }
            }
        }
    }

    // epilogue 1: h = relu(acc + bias) -> split-bf16 LDS planes
#pragma unroll
    for (int mt = 0; mt < 2; ++mt)
#pragma unroll
        for (int nt = 0; nt < 4; ++nt) {
            int col = nt * 16 + r16;
            float bv = bias[col];
#pragma unroll
            for (int reg = 0; reg < 4; ++reg) {
                int rl = w * 32 + mt * 16 + kg * 4 + reg;
                float h = fmaxf(acc[mt][nt][reg] + bv, 0.f);
                unsigned short hb = f2bf(h);
                Hh[rl][col] = hb;
                Hl[rl][col] = f2bf(h - bf2f(hb));
            }
        }
    __syncthreads();

    f32x4 acc2[2][4];
#pragma unroll
    for (int i = 0; i < 2; ++i)
#pragma unroll
        for (int j = 0; j < 4; ++j) acc2[i][j] = (f32x4){0.f, 0.f, 0.f, 0.f};

#pragma unroll
    for (int ks = 0; ks < 2; ++ks) {
        bf16x8 ah[2], al[2];
#pragma unroll
        for (int mt = 0; mt < 2; ++mt) {
            int rl = w * 32 + mt * 16 + r16;
            ah[mt] = *reinterpret_cast<const bf16x8*>(&Hh[rl][ks * 32 + kg * 8]);
            al[mt] = *reinterpret_cast<const bf16x8*>(&Hl[rl][ks * 32 + kg * 8]);
        }
#pragma unroll
        for (int nt = 0; nt < 4; ++nt) {
            const unsigned short* wb =
                Wlpk + (size_t)(((ks * 4 + nt) * 2)) * 512 + lane * 8;
            bf16x8 bh = *reinterpret_cast<const bf16x8*>(wb);
            bf16x8 blo = *reinterpret_cast<const bf16x8*>(wb + 512);
#pragma unroll
            for (int mt = 0; mt < 2; ++mt) {
                acc2[mt][nt] = __builtin_amdgcn_mfma_f32_16x16x32_bf16(ah[mt], bh,  acc2[mt][nt], 0, 0, 0);
                acc2[mt][nt] = __builtin_amdgcn_mfma_f32_16x16x32_bf16(ah[mt], blo, acc2[mt][nt], 0, 0, 0);
                acc2[mt][nt] = __builtin_amdgcn_mfma_f32_16x16x32_bf16(al[mt], bh,  acc2[mt][nt], 0, 0, 0);
            }
        }
    }

    // epilogue 2: out = (h2 + bl) * dg
#pragma unroll
    for (int mt = 0; mt < 2; ++mt)
#pragma unroll
        for (int nt = 0; nt < 4; ++nt) {
            int col = nt * 16 + r16;
            float bv = bl[col];
#pragma unroll
            for (int reg = 0; reg < 4; ++reg) {
                int rl = w * 32 + mt * 16 + kg * 4 + reg;
                if (m0 + rl < rowsEff) {
                    size_t idx = (size_t)(r0 + m0 + rl) * 64 + col;
                    outb[idx] = (acc2[mt][nt][reg] + bv) * dgb[idx];
                }
            }
        }
}

// ---------------------------------------------------------------------------
// pooling scatter: rank-translated compact read, one wave per nnz.
// ---------------------------------------------------------------------------
__global__ __launch_bounds__(256) void pool_scatter(
        const int* __restrict__ prow, const int* __restrict__ pcol,
        const float* __restrict__ pval, const int* __restrict__ poolRank,
        const float* __restrict__ outb, float* __restrict__ out) {
    int t = blockIdx.x * 256 + threadIdx.x;
    int i = t >> 6, d = t & 63;
    if (i >= NPERM_C) return;
    int r = prow[i], c = pcol[i];
    float v = pval[i];
    int cr = poolRank[c];
    atomicAdd(&out[(size_t)r * 64 + d], v * outb[(size_t)cr * 64 + d]);
}

extern "C" void kernel_launch(void* const* d_in, const int* in_sizes, int n_in,
                              void* d_out, int out_size, void* d_ws, size_t ws_size,
                              hipStream_t stream) {
    const float* x       = (const float*)d_in[0];
    const float* efeat   = (const float*)d_in[1];
    const float* degs    = (const float*)d_in[2];
    const int*   n2p_row = (const int*)d_in[3];
    const int*   n2p_col = (const int*)d_in[4];
    const float* n2p_val = (const float*)d_in[5];
    const int*   e2p_row = (const int*)d_in[6];
    const int*   e2p_col = (const int*)d_in[7];
    const float* e2p_val = (const float*)d_in[8];
    const int*   pool_row = (const int*)d_in[9];
    const int*   pool_col = (const int*)d_in[10];
    const float* pool_val = (const float*)d_in[11];
    const float* weights = (const float*)d_in[12];
    const float* bias    = (const float*)d_in[13];
    const float* W0      = (const float*)d_in[14];
    const float* b0      = (const float*)d_in[15];
    const float* W1      = (const float*)d_in[16];
    const float* b1      = (const float*)d_in[17];
    const float* Wl      = (const float*)d_in[18];
    const float* bl      = (const float*)d_in[19];
    float* out = (float*)d_out;

    // workspace layout (4B elems)
    uint2* suv      = (uint2*)d_ws;                    // 16,000,000
    int*   pOff     = (int*)(suv + 8000000);           //  4,000,064
    int*   pCur     = pOff + 4000064;                  //  4,000,000
    int*   bsum     = pCur + 4000000;                  //      2,048
    int*   poolCnt  = bsum + 2048;                     //    250,000
    int*   poolRank = poolCnt + 250000;                //    250,000
    int*   act      = poolRank + 250000;               //    250,000
    int*   bsum2    = act + 250000;                    //        256
    int*   nActB    = bsum2 + 256;                     //         16
    unsigned short* Bpk  = (unsigned short*)(nActB + 16);   // 131072 us = 65536
    unsigned short* Wlpk = Bpk + 131072;                    //   8192 us =  4096
    float* degD = (float*)(Wlpk + 8192);               //  1,000,000
    float* dgb  = degD + 1000000;                      // 16,000,000
    float* outb = dgb;                                 // alias (same-idx RAW)
    unsigned short* nfH = (unsigned short*)(dgb + 16000000);

    const long long base_elems = 16000000LL + 4000064 + 4000000 + 2048 +
                                 250000 * 3 + 256 + 16 + 65536 + 4096 +
                                 1000000 + 16000000;   // 41,822,016
    long long availf = (long long)(ws_size / 4) - base_elems;
    long long chl = availf / 1024;   // per row: 2 planes * 16*64 * 2B = 4 KB
    if (chl > NPERM_C) chl = NPERM_C;
    int CH = (int)(chl & ~127LL);
    if (CH < 128) {
        hipMemsetAsync(d_out, 0, (size_t)out_size * 4, stream);
        return;
    }
    unsigned short* nfL = nfH + (size_t)CH * 1024;

    hipMemsetAsync(pCur, 0, (size_t)P_C * 4, stream);
    hipMemsetAsync(poolCnt, 0, (size_t)NPERM_C * 4, stream);
    hipMemsetAsync(out, 0, (size_t)G_C * 64 * 4, stream);

    repack_bpk<<<512, 256, 0, stream>>>(weights, Bpk);
    repack_wlpk<<<32, 256, 0, stream>>>(Wl, Wlpk);

    pool_hist<<<(NPERM_C + 255) / 256, 256, 0, stream>>>(pool_col, poolCnt);
    pool_scan_local<<<NB2, 256, 0, stream>>>(poolCnt, poolRank, bsum2);
    pool_scan_top<<<1, 256, 0, stream>>>(bsum2);
    pool_scan_add<<<NB2, 256, 0, stream>>>(poolCnt, poolRank, bsum2, act, nActB);

    hist<<<31250, 256, 0, stream>>>(n2p_row, e2p_row, poolCnt, pCur);
    scan_local<<<NB1, 256, 0, stream>>>(pCur, pOff, bsum);
    scan_top<<<1, 256, 0, stream>>>(bsum);
    scan_add<<<NB1, 256, 0, stream>>>(pOff, bsum, pCur);
    scat<<<31250, 256, 0, stream>>>(n2p_row, n2p_col, n2p_val,
                                    e2p_row, e2p_col, e2p_val,
                                    poolCnt, pCur, suv);

    for (int c0 = 0; c0 < NPERM_C; c0 += CH) {
        int rows = NPERM_C - c0; if (rows > CH) rows = CH;
        gather_nfeat<<<(rows + 7) / 8, 256, 0, stream>>>(
            suv, pOff, x, efeat, degs, act, nActB, nfH, nfL, degD, c0, rows);
        dg_gemm<<<(rows + 63) / 64, 256, 0, stream>>>(
            degD, W0, b0, W1, b1, nActB, dgb, c0, rows);
        gemm_mfma<<<(rows + 127) / 128, 256, 0, stream>>>(
            nfH, nfL, Bpk, Wlpk, bias, bl, dgb, nActB, outb, c0, rows);
    }

    pool_scatter<<<62500, 256, 0, stream>>>(pool_row, pool_col, pool_val,
                                            poolRank, outb, out);
}

// Round 7
// 1659.012 us; speedup vs baseline: 1.6008x; 1.6008x over previous
//
#include <hip/hip_runtime.h>

#define NPERM_C 250000
#define P_C     4000000          // slots = NPERM * 16
#define G_C     4096
#define NB1     1954             // ceil(P_C / 2048) big scan
#define NB2     123              // ceil(NPERM_C / 2048) pool scan

typedef __attribute__((ext_vector_type(8))) short bf16x8;
typedef __attribute__((ext_vector_type(4))) float f32x4;

static __device__ __forceinline__ unsigned short f2bf(float f) {
    unsigned u = __float_as_uint(f);
    unsigned r = (u + 0x7fffu + ((u >> 16) & 1u)) >> 16;   // RNE
    return (unsigned short)r;
}
static __device__ __forceinline__ float bf2f(unsigned short s) {
    return __uint_as_float(((unsigned)s) << 16);
}

// ---------------------------------------------------------------------------
// fragment-ordered split-bf16 weight tables
// ---------------------------------------------------------------------------
__global__ void repack_bpk(const float* __restrict__ w, unsigned short* __restrict__ bpk) {
    int o = blockIdx.x * 256 + threadIdx.x;          // 131072 total
    int j = o & 7, lane = (o >> 3) & 63, h = (o >> 9) & 1;
    int nt = (o >> 10) & 3, ks = (o >> 12) & 1, l = o >> 13;
    int b = ks * 32 + (lane >> 4) * 8 + j;
    int c = nt * 16 + (lane & 15);
    float wv = w[(b * 64 + c) * 16 + l];
    unsigned short hb = f2bf(wv);
    bpk[o] = (h == 0) ? hb : f2bf(wv - bf2f(hb));
}

__global__ void repack_wlpk(const float* __restrict__ wl, unsigned short* __restrict__ wpk) {
    int o = blockIdx.x * 256 + threadIdx.x;          // 8192 total
    int j = o & 7, lane = (o >> 3) & 63, h = (o >> 9) & 1;
    int nt = (o >> 10) & 3, ks = o >> 12;
    int k = ks * 32 + (lane >> 4) * 8 + j;
    int c2 = nt * 16 + (lane & 15);
    float wv = wl[c2 * 64 + k];
    unsigned short hb = f2bf(wv);
    wpk[o] = (h == 0) ? hb : f2bf(wv - bf2f(hb));
}

// ---------------------------------------------------------------------------
// pool reference histogram: poolCnt[c] = #times perm row c is pooled.
// ---------------------------------------------------------------------------
__global__ __launch_bounds__(256) void pool_hist(const int* __restrict__ pcol,
                                                 int* __restrict__ poolCnt) {
    int i = blockIdx.x * 256 + threadIdx.x;
    if (i < NPERM_C) atomicAdd(&poolCnt[pcol[i]], 1);
}

// active-row compaction scan (flag = cnt!=0), deterministic.
__global__ __launch_bounds__(256) void pool_scan_local(const int* __restrict__ poolCnt,
                                                       int* __restrict__ poolRk,
                                                       int* __restrict__ bsum2) {
    __shared__ int ts[256];
    int b = blockIdx.x, t = threadIdx.x;
    int base = b * 2048 + t * 8;
    int v[8]; int s = 0;
#pragma unroll
    for (int i = 0; i < 8; ++i) {
        int idx = base + i;
        v[i] = (idx < NPERM_C) ? (poolCnt[idx] != 0) : 0;
        s += v[i];
    }
    ts[t] = s;
    __syncthreads();
    for (int ofs = 1; ofs < 256; ofs <<= 1) {
        int xv = (t >= ofs) ? ts[t - ofs] : 0;
        __syncthreads();
        ts[t] += xv;
        __syncthreads();
    }
    int run = ts[t] - s;
    if (t == 255) bsum2[b] = ts[255];
#pragma unroll
    for (int i = 0; i < 8; ++i) {
        int idx = base + i;
        if (idx < NPERM_C) poolRk[idx] = run;
        run += v[i];
    }
}

__global__ void pool_scan_top(int* __restrict__ bsum2) {
    __shared__ int ts[256];
    int t = threadIdx.x;
    int v = (t < NB2) ? bsum2[t] : 0;
    ts[t] = v;
    __syncthreads();
    for (int ofs = 1; ofs < 256; ofs <<= 1) {
        int xv = (t >= ofs) ? ts[t - ofs] : 0;
        __syncthreads();
        ts[t] += xv;
        __syncthreads();
    }
    if (t < NB2) bsum2[t] = ts[t] - v;
}

// finalize: poolRk[idx] := ((rank)<<1) | activeFlag ; nActB[0] = #active
__global__ __launch_bounds__(256) void pool_scan_add(const int* __restrict__ poolCnt,
                                                     int* __restrict__ poolRk,
                                                     const int* __restrict__ bsum2,
                                                     int* __restrict__ nActB) {
    int b = blockIdx.x, t = threadIdx.x;
    int add = bsum2[b];
    int base = b * 2048 + t * 8;
#pragma unroll
    for (int i = 0; i < 8; ++i) {
        int idx = base + i;
        if (idx < NPERM_C) {
            int flag = poolCnt[idx] != 0;
            int o = poolRk[idx] + add;
            poolRk[idx] = (o << 1) | flag;
            if (idx == NPERM_C - 1) nActB[0] = o + flag;
        }
    }
}

// ---------------------------------------------------------------------------
// slot histogram over ACTIVE rows, in COMPACT slot space.
// ---------------------------------------------------------------------------
__global__ __launch_bounds__(256) void hist(const int* __restrict__ r1,
                                            const int* __restrict__ r2,
                                            const int* __restrict__ poolRk,
                                            int* __restrict__ cnt) {
    int i = blockIdx.x * 256 + threadIdx.x;
    int r;
    if (i < P_C)            r = r1[i];
    else if (i < 2 * P_C)   r = r2[i - P_C];
    else return;
    int info = poolRk[r >> 4];
    if (info & 1) atomicAdd(&cnt[(info >> 1) * 16 + (r & 15)], 1);
}

// big exclusive scan over 4M slot counts.
__global__ __launch_bounds__(256) void scan_local(const int* __restrict__ cnt,
                                                  int* __restrict__ off,
                                                  int* __restrict__ bsum) {
    __shared__ int ts[256];
    int b = blockIdx.x, t = threadIdx.x;
    int base = b * 2048 + t * 8;
    int v[8]; int s = 0;
#pragma unroll
    for (int i = 0; i < 8; ++i) {
        int idx = base + i;
        v[i] = (idx < P_C) ? cnt[idx] : 0;
        s += v[i];
    }
    ts[t] = s;
    __syncthreads();
    for (int ofs = 1; ofs < 256; ofs <<= 1) {
        int xv = (t >= ofs) ? ts[t - ofs] : 0;
        __syncthreads();
        ts[t] += xv;
        __syncthreads();
    }
    int run = ts[t] - s;
    if (t == 255) bsum[b] = ts[255];
#pragma unroll
    for (int i = 0; i < 8; ++i) {
        int idx = base + i;
        if (idx < P_C) off[idx] = run;
        run += v[i];
    }
}

__global__ void scan_top(int* __restrict__ bsum) {
    __shared__ int ts[256];
    int t = threadIdx.x;
    int base = t * 8;
    int v[8]; int s = 0;
#pragma unroll
    for (int i = 0; i < 8; ++i) {
        int idx = base + i;
        v[i] = (idx < NB1) ? bsum[idx] : 0;
        s += v[i];
    }
    ts[t] = s;
    __syncthreads();
    for (int ofs = 1; ofs < 256; ofs <<= 1) {
        int xv = (t >= ofs) ? ts[t - ofs] : 0;
        __syncthreads();
        ts[t] += xv;
        __syncthreads();
    }
    int run = ts[t] - s;
#pragma unroll
    for (int i = 0; i < 8; ++i) {
        int idx = base + i;
        if (idx < NB1) bsum[idx] = run;
        run += v[i];
    }
}

__global__ __launch_bounds__(256) void scan_add(int* __restrict__ off,
                                                const int* __restrict__ bsum,
                                                int* __restrict__ cur) {
    int b = blockIdx.x, t = threadIdx.x;
    int add = bsum[b];
    int base = b * 2048 + t * 8;
#pragma unroll
    for (int i = 0; i < 8; ++i) {
        int idx = base + i;
        if (idx < P_C) {
            int o = off[idx] + add;
            if (idx == P_C - 1) off[P_C] = o + cur[idx];  // cur still holds count
            off[idx] = o;
            cur[idx] = o;
        }
    }
}

// ---------------------------------------------------------------------------
// scatter active entries to sorted position (compact slot space).
// ---------------------------------------------------------------------------
__global__ __launch_bounds__(256) void scat(
        const int* __restrict__ r1, const int* __restrict__ c1, const float* __restrict__ v1,
        const int* __restrict__ r2, const int* __restrict__ c2, const float* __restrict__ v2,
        const int* __restrict__ poolRk,
        int* __restrict__ cur, uint2* __restrict__ suv) {
    int i = blockIdx.x * 256 + threadIdx.x;
    int row; unsigned key; float val;
    if (i < P_C)          { row = r1[i]; key = (unsigned)c1[i]; val = v1[i]; }
    else if (i < 2 * P_C) { int j = i - P_C; row = r2[j]; key = (unsigned)c2[j] | 0x100000u; val = v2[j]; }
    else return;
    int info = poolRk[row >> 4];
    if (!(info & 1)) return;
    int pos = atomicAdd(&cur[(info >> 1) * 16 + (row & 15)], 1);
    suv[pos] = make_uint2(key, __float_as_uint(val));
}

// ---------------------------------------------------------------------------
// CSR gather (round-5 structure, compact pOff — no act indirection).
// float4-per-lane: 16-lane group owns 2 chains; wave = 8 slots;
// block = 2 compact rows. Writes split-bf16 planes + degree-gate slots.
// ---------------------------------------------------------------------------
__global__ __launch_bounds__(256) void gather_nfeat(
        const uint2* __restrict__ suv, const int* __restrict__ pOff,
        const float* __restrict__ x, const float* __restrict__ efeat,
        const float* __restrict__ degs, const int* __restrict__ nActB,
        unsigned short* __restrict__ nfH, unsigned short* __restrict__ nfL,
        float* __restrict__ degD, int row0, int rows) {
    int nAct = nActB[0];
    int t = threadIdx.x;
    int w = t >> 6, lane = t & 63;
    int g = lane >> 4, t16 = lane & 15;
    int cr = row0 + blockIdx.x * 2 + (w >> 1);
    int rend = row0 + rows; if (rend > nAct) rend = nAct;
    if (cr >= rend) return;                 // wave-uniform
    int posA = (w & 1) * 8 + g * 2;
    int posB = posA + 1;
    int sA = cr * 16 + posA;
    int iA = pOff[sA];
    int eA = pOff[sA + 1];
    int iB = eA;
    int eB = pOff[sA + 2];
    bool needA = (posA == 0) || (posA == 10);
    bool needB = (posB == 5) || (posB == 15);
    float4 aA = {0.f, 0.f, 0.f, 0.f}, aB = {0.f, 0.f, 0.f, 0.f};
    float dA = 0.f, dB = 0.f;
    while ((iA < eA) || (iB < eB)) {
        bool hA = iA < eA, hB = iB < eB;
        uint2 kvA, kvB;
        if (hA) kvA = suv[iA];
        if (hB) kvB = suv[iB];
        if (hA) {
            unsigned k = kvA.x; float v = __uint_as_float(kvA.y);
            const float* f = (k & 0x100000u) ? efeat : x;
            float4 fv = *reinterpret_cast<const float4*>(
                f + (size_t)(k & 0xFFFFFu) * 64 + t16 * 4);
            aA.x = fmaf(v, fv.x, aA.x); aA.y = fmaf(v, fv.y, aA.y);
            aA.z = fmaf(v, fv.z, aA.z); aA.w = fmaf(v, fv.w, aA.w);
            if (needA && !(k & 0x100000u)) dA = fmaf(v, degs[k & 0xFFFFFu], dA);
            ++iA;
        }
        if (hB) {
            unsigned k = kvB.x; float v = __uint_as_float(kvB.y);
            const float* f = (k & 0x100000u) ? efeat : x;
            float4 fv = *reinterpret_cast<const float4*>(
                f + (size_t)(k & 0xFFFFFu) * 64 + t16 * 4);
            aB.x = fmaf(v, fv.x, aB.x); aB.y = fmaf(v, fv.y, aB.y);
            aB.z = fmaf(v, fv.z, aB.z); aB.w = fmaf(v, fv.w, aB.w);
            if (needB && !(k & 0x100000u)) dB = fmaf(v, degs[k & 0xFFFFFu], dB);
            ++iB;
        }
    }
    size_t o = ((size_t)(cr - row0) * 16 + posA) * 64 + t16 * 4;
    ushort4 h4, l4;
    h4.x = f2bf(aA.x); l4.x = f2bf(aA.x - bf2f(h4.x));
    h4.y = f2bf(aA.y); l4.y = f2bf(aA.y - bf2f(h4.y));
    h4.z = f2bf(aA.z); l4.z = f2bf(aA.z - bf2f(h4.z));
    h4.w = f2bf(aA.w); l4.w = f2bf(aA.w - bf2f(h4.w));
    *reinterpret_cast<ushort4*>(nfH + o) = h4;
    *reinterpret_cast<ushort4*>(nfL + o) = l4;
    h4.x = f2bf(aB.x); l4.x = f2bf(aB.x - bf2f(h4.x));
    h4.y = f2bf(aB.y); l4.y = f2bf(aB.y - bf2f(h4.y));
    h4.z = f2bf(aB.z); l4.z = f2bf(aB.z - bf2f(h4.z));
    h4.w = f2bf(aB.w); l4.w = f2bf(aB.w - bf2f(h4.w));
    *reinterpret_cast<ushort4*>(nfH + o + 64) = h4;
    *reinterpret_cast<ushort4*>(nfL + o + 64) = l4;
    if (t16 == 0) {
        if (needA) degD[(size_t)cr * 4 + posA / 5] = dA;
        if (needB) degD[(size_t)cr * 4 + posB / 5] = dB;
    }
}

// ---------------------------------------------------------------------------
// degree-gate MLP over compact rows [r0, min(r0+rows, nAct)).
// ---------------------------------------------------------------------------
__global__ __launch_bounds__(256) void dg_gemm(
        const float* __restrict__ degD,
        const float* __restrict__ W0, const float* __restrict__ b0,
        const float* __restrict__ W1, const float* __restrict__ b1,
        const int* __restrict__ nActB,
        float* __restrict__ dgb, int r0, int rows) {
    __shared__ float hidT[128][68];   // [h][r]
    __shared__ float w1T[128][68];    // [h][c]
    __shared__ float dloc[64][4];
    __shared__ float w0s[128][5];
    int nAct = nActB[0];
    int rend = r0 + rows; if (rend > nAct) rend = nAct;
    int t = threadIdx.x;
    int m0 = r0 + blockIdx.x * 64;
    if (m0 >= rend) return;

    {
        int r = t >> 2, j = t & 3;
        int gr = m0 + r; if (gr >= rend) gr = rend - 1;
        dloc[r][j] = degD[(size_t)gr * 4 + j];
    }
    if (t < 128) {
        w0s[t][0] = W0[t * 4 + 0]; w0s[t][1] = W0[t * 4 + 1];
        w0s[t][2] = W0[t * 4 + 2]; w0s[t][3] = W0[t * 4 + 3];
        w0s[t][4] = b0[t];
    }
    for (int s = 0; s < 32; ++s) {
        int idx = t + s * 256;
        w1T[idx & 127][idx >> 7] = W1[idx];
    }
    __syncthreads();
    for (int s = 0; s < 32; ++s) {
        int idx = t + s * 256;
        int h = idx & 127, r = idx >> 7;
        float v = w0s[h][4] + dloc[r][0] * w0s[h][0] + dloc[r][1] * w0s[h][1]
                            + dloc[r][2] * w0s[h][2] + dloc[r][3] * w0s[h][3];
        hidT[h][r] = fmaxf(v, 0.f);
    }
    __syncthreads();

    int tm = t >> 4, tn = t & 15;
    float acc[4][4] = {};
#pragma unroll 8
    for (int k = 0; k < 128; ++k) {
        float4 a = *reinterpret_cast<const float4*>(&hidT[k][tm * 4]);
        float4 b = *reinterpret_cast<const float4*>(&w1T[k][tn * 4]);
        acc[0][0] = fmaf(a.x, b.x, acc[0][0]); acc[0][1] = fmaf(a.x, b.y, acc[0][1]);
        acc[0][2] = fmaf(a.x, b.z, acc[0][2]); acc[0][3] = fmaf(a.x, b.w, acc[0][3]);
        acc[1][0] = fmaf(a.y, b.x, acc[1][0]); acc[1][1] = fmaf(a.y, b.y, acc[1][1]);
        acc[1][2] = fmaf(a.y, b.z, acc[1][2]); acc[1][3] = fmaf(a.y, b.w, acc[1][3]);
        acc[2][0] = fmaf(a.z, b.x, acc[2][0]); acc[2][1] = fmaf(a.z, b.y, acc[2][1]);
        acc[2][2] = fmaf(a.z, b.z, acc[2][2]); acc[2][3] = fmaf(a.z, b.w, acc[2][3]);
        acc[3][0] = fmaf(a.w, b.x, acc[3][0]); acc[3][1] = fmaf(a.w, b.y, acc[3][1]);
        acc[3][2] = fmaf(a.w, b.z, acc[3][2]); acc[3][3] = fmaf(a.w, b.w, acc[3][3]);
    }
    float bb[4] = {b1[tn * 4 + 0], b1[tn * 4 + 1], b1[tn * 4 + 2], b1[tn * 4 + 3]};
#pragma unroll
    for (int i = 0; i < 4; ++i) {
        int grow = m0 + tm * 4 + i;
        if (grow < rend) {
            float4 o = {acc[i][0] + bb[0], acc[i][1] + bb[1],
                        acc[i][2] + bb[2], acc[i][3] + bb[3]};
            *reinterpret_cast<float4*>(&dgb[(size_t)grow * 64 + tn * 4]) = o;
        }
    }
}

// ---------------------------------------------------------------------------
// MFMA einsum + epilogue (split-bf16, 3 products) over compact rows.
// ---------------------------------------------------------------------------
__global__ __launch_bounds__(256) void gemm_mfma(
        const unsigned short* __restrict__ nfH, const unsigned short* __restrict__ nfL,
        const unsigned short* __restrict__ Bpk, const unsigned short* __restrict__ Wlpk,
        const float* __restrict__ bias, const float* __restrict__ bl,
        const float* __restrict__ dgb, const int* __restrict__ nActB,
        float* __restrict__ outb, int r0, int rows) {
    __shared__ unsigned short Hh[128][72];
    __shared__ unsigned short Hl[128][72];
    int nAct = nActB[0];
    int rowsEff = rows; if (r0 + rowsEff > nAct) rowsEff = nAct - r0;
    int t = threadIdx.x, lane = t & 63, w = t >> 6;
    int m0 = blockIdx.x * 128;
    if (m0 >= rowsEff) return;
    int r16 = lane & 15, kg = lane >> 4;

    f32x4 acc[2][4];
#pragma unroll
    for (int i = 0; i < 2; ++i)
#pragma unroll
        for (int j = 0; j < 4; ++j) acc[i][j] = (f32x4){0.f, 0.f, 0.f, 0.f};

    for (int l = 0; l < 16; ++l) {
#pragma unroll
        for (int ks = 0; ks < 2; ++ks) {
            bf16x8 ah[2], al[2];
#pragma unroll
            for (int mt = 0; mt < 2; ++mt) {
                int lr = m0 + w * 32 + mt * 16 + r16;
                if (lr >= rowsEff) lr = rowsEff - 1;
                size_t off = ((size_t)lr * 16 + l) * 64 + ks * 32 + kg * 8;
                ah[mt] = *reinterpret_cast<const bf16x8*>(nfH + off);
                al[mt] = *reinterpret_cast<const bf16x8*>(nfL + off);
            }
#pragma unroll
            for (int nt = 0; nt < 4; ++nt) {
                const unsigned short* bb =
                    Bpk + (size_t)(((l * 2 + ks) * 4 + nt) * 2) * 512 + lane * 8;
                bf16x8 bh = *reinterpret_cast<const bf16x8*>(bb);
                bf16x8 blo = *reinterpret_cast<const bf16x8*>(bb + 512);
#pragma unroll
                for (int mt = 0; mt < 2; ++mt) {
                    acc[mt][nt] = __builtin_amdgcn_mfma_f32_16x16x32_bf16(ah[mt], bh,  acc[mt][nt], 0, 0, 0);
                    acc[mt][nt] = __builtin_amdgcn_mfma_f32_16x16x32_bf16(ah[mt], blo, acc[mt][nt], 0, 0, 0);
                    acc[mt][nt] = __builtin_amdgcn_mfma_f32_16x16x32_bf16(al[mt], bh,  acc[mt][nt], 0, 0, 0);
                }
            }
        }
    }

    // epilogue 1: h = relu(acc + bias) -> split-bf16 LDS planes
#pragma unroll
    for (int mt = 0; mt < 2; ++mt)
#pragma unroll
        for (int nt = 0; nt < 4; ++nt) {
            int col = nt * 16 + r16;
            float bv = bias[col];
#pragma unroll
            for (int reg = 0; reg < 4; ++reg) {
                int rl = w * 32 + mt * 16 + kg * 4 + reg;
                float h = fmaxf(acc[mt][nt][reg] + bv, 0.f);
                unsigned short hb = f2bf(h);
                Hh[rl][col] = hb;
                Hl[rl][col] = f2bf(h - bf2f(hb));
            }
        }
    __syncthreads();

    f32x4 acc2[2][4];
#pragma unroll
    for (int i = 0; i < 2; ++i)
#pragma unroll
        for (int j = 0; j < 4; ++j) acc2[i][j] = (f32x4){0.f, 0.f, 0.f, 0.f};

#pragma unroll
    for (int ks = 0; ks < 2; ++ks) {
        bf16x8 ah[2], al[2];
#pragma unroll
        for (int mt = 0; mt < 2; ++mt) {
            int rl = w * 32 + mt * 16 + r16;
            ah[mt] = *reinterpret_cast<const bf16x8*>(&Hh[rl][ks * 32 + kg * 8]);
            al[mt] = *reinterpret_cast<const bf16x8*>(&Hl[rl][ks * 32 + kg * 8]);
        }
#pragma unroll
        for (int nt = 0; nt < 4; ++nt) {
            const unsigned short* wb =
                Wlpk + (size_t)(((ks * 4 + nt) * 2)) * 512 + lane * 8;
            bf16x8 bh = *reinterpret_cast<const bf16x8*>(wb);
            bf16x8 blo = *reinterpret_cast<const bf16x8*>(wb + 512);
#pragma unroll
            for (int mt = 0; mt < 2; ++mt) {
                acc2[mt][nt] = __builtin_amdgcn_mfma_f32_16x16x32_bf16(ah[mt], bh,  acc2[mt][nt], 0, 0, 0);
                acc2[mt][nt] = __builtin_amdgcn_mfma_f32_16x16x32_bf16(ah[mt], blo, acc2[mt][nt], 0, 0, 0);
                acc2[mt][nt] = __builtin_amdgcn_mfma_f32_16x16x32_bf16(al[mt], bh,  acc2[mt][nt], 0, 0, 0);
            }
        }
    }

    // epilogue 2: out = (h2 + bl) * dg
#pragma unroll
    for (int mt = 0; mt < 2; ++mt)
#pragma unroll
        for (int nt = 0; nt < 4; ++nt) {
            int col = nt * 16 + r16;
            float bv = bl[col];
#pragma unroll
            for (int reg = 0; reg < 4; ++reg) {
                int rl = w * 32 + mt * 16 + kg * 4 + reg;
                if (m0 + rl < rowsEff) {
                    size_t idx = (size_t)(r0 + m0 + rl) * 64 + col;
                    outb[idx] = (acc2[mt][nt][reg] + bv) * dgb[idx];
                }
            }
        }
}

// ---------------------------------------------------------------------------
// pooling scatter: rank-translated compact read, one wave per nnz.
// ---------------------------------------------------------------------------
__global__ __launch_bounds__(256) void pool_scatter(
        const int* __restrict__ prow, const int* __restrict__ pcol,
        const float* __restrict__ pval, const int* __restrict__ poolRk,
        const float* __restrict__ outb, float* __restrict__ out) {
    int t = blockIdx.x * 256 + threadIdx.x;
    int i = t >> 6, d = t & 63;
    if (i >= NPERM_C) return;
    int r = prow[i], c = pcol[i];
    float v = pval[i];
    int cr = poolRk[c] >> 1;
    atomicAdd(&out[(size_t)r * 64 + d], v * outb[(size_t)cr * 64 + d]);
}

extern "C" void kernel_launch(void* const* d_in, const int* in_sizes, int n_in,
                              void* d_out, int out_size, void* d_ws, size_t ws_size,
                              hipStream_t stream) {
    const float* x       = (const float*)d_in[0];
    const float* efeat   = (const float*)d_in[1];
    const float* degs    = (const float*)d_in[2];
    const int*   n2p_row = (const int*)d_in[3];
    const int*   n2p_col = (const int*)d_in[4];
    const float* n2p_val = (const float*)d_in[5];
    const int*   e2p_row = (const int*)d_in[6];
    const int*   e2p_col = (const int*)d_in[7];
    const float* e2p_val = (const float*)d_in[8];
    const int*   pool_row = (const int*)d_in[9];
    const int*   pool_col = (const int*)d_in[10];
    const float* pool_val = (const float*)d_in[11];
    const float* weights = (const float*)d_in[12];
    const float* bias    = (const float*)d_in[13];
    const float* W0      = (const float*)d_in[14];
    const float* b0      = (const float*)d_in[15];
    const float* W1      = (const float*)d_in[16];
    const float* b1      = (const float*)d_in[17];
    const float* Wl      = (const float*)d_in[18];
    const float* bl      = (const float*)d_in[19];
    float* out = (float*)d_out;

    // workspace layout (4B elems)
    uint2* suv      = (uint2*)d_ws;                    // 16,000,000
    int*   pOff     = (int*)(suv + 8000000);           //  4,000,064
    int*   pCur     = pOff + 4000064;                  //  4,000,000
    int*   bsum     = pCur + 4000000;                  //      2,048
    int*   poolCnt  = bsum + 2048;                     //    250,000
    int*   poolRk   = poolCnt + 250000;                //    250,000
    int*   bsum2    = poolRk + 250000;                 //        256
    int*   nActB    = bsum2 + 256;                     //         16
    unsigned short* Bpk  = (unsigned short*)(nActB + 16);   // 131072 us = 65536
    unsigned short* Wlpk = Bpk + 131072;                    //   8192 us =  4096
    float* degD = (float*)(Wlpk + 8192);               //  1,000,000
    float* dgb  = degD + 1000000;                      // 16,000,000
    float* outb = dgb;                                 // alias (same-idx RAW)
    unsigned short* nfH = (unsigned short*)(dgb + 16000000);

    const long long base_elems = 16000000LL + 4000064 + 4000000 + 2048 +
                                 250000 * 2 + 256 + 16 + 65536 + 4096 +
                                 1000000 + 16000000;   // 41,572,016
    long long availf = (long long)(ws_size / 4) - base_elems;
    long long chl = availf / 1024;   // per row: 2 planes * 16*64 * 2B = 4 KB
    if (chl > NPERM_C) chl = NPERM_C;
    int CH = (int)(chl & ~127LL);
    if (CH > 32768) CH = 32768;      // keep planes L3-resident gather->gemm
    if (CH < 128) {
        hipMemsetAsync(d_out, 0, (size_t)out_size * 4, stream);
        return;
    }
    unsigned short* nfL = nfH + (size_t)CH * 1024;

    hipMemsetAsync(pCur, 0, (size_t)P_C * 4, stream);
    hipMemsetAsync(poolCnt, 0, (size_t)NPERM_C * 4, stream);
    hipMemsetAsync(out, 0, (size_t)G_C * 64 * 4, stream);

    repack_bpk<<<512, 256, 0, stream>>>(weights, Bpk);
    repack_wlpk<<<32, 256, 0, stream>>>(Wl, Wlpk);

    pool_hist<<<(NPERM_C + 255) / 256, 256, 0, stream>>>(pool_col, poolCnt);
    pool_scan_local<<<NB2, 256, 0, stream>>>(poolCnt, poolRk, bsum2);
    pool_scan_top<<<1, 256, 0, stream>>>(bsum2);
    pool_scan_add<<<NB2, 256, 0, stream>>>(poolCnt, poolRk, bsum2, nActB);

    hist<<<31250, 256, 0, stream>>>(n2p_row, e2p_row, poolRk, pCur);
    scan_local<<<NB1, 256, 0, stream>>>(pCur, pOff, bsum);
    scan_top<<<1, 256, 0, stream>>>(bsum);
    scan_add<<<NB1, 256, 0, stream>>>(pOff, bsum, pCur);
    scat<<<31250, 256, 0, stream>>>(n2p_row, n2p_col, n2p_val,
                                    e2p_row, e2p_col, e2p_val,
                                    poolRk, pCur, suv);

    for (int c0 = 0; c0 < NPERM_C; c0 += CH) {
        int rows = NPERM_C - c0; if (rows > CH) rows = CH;
        gather_nfeat<<<(rows + 1) / 2, 256, 0, stream>>>(
            suv, pOff, x, efeat, degs, nActB, nfH, nfL, degD, c0, rows);
        dg_gemm<<<(rows + 63) / 64, 256, 0, stream>>>(
            degD, W0, b0, W1, b1, nActB, dgb, c0, rows);
        gemm_mfma<<<(rows + 127) / 128, 256, 0, stream>>>(
            nfH, nfL, Bpk, Wlpk, bias, bl, dgb, nActB, outb, c0, rows);
    }

    pool_scatter<<<62500, 256, 0, stream>>>(pool_row, pool_col, pool_val,
                                            poolRk, outb, out);
}

// Round 8
// 1399.141 us; speedup vs baseline: 1.8981x; 1.1857x over previous
//
#include <hip/hip_runtime.h>

#define NPERM_C 250000
#define P_C     4000000          // slots = NPERM * 16
#define G_C     4096
#define NB1     1954             // ceil(P_C / 2048) big scan
#define NB2     123              // ceil(NPERM_C / 2048) pool scan

typedef __attribute__((ext_vector_type(8))) short bf16x8;
typedef __attribute__((ext_vector_type(4))) float f32x4;

static __device__ __forceinline__ unsigned short f2bf(float f) {
    unsigned u = __float_as_uint(f);
    unsigned r = (u + 0x7fffu + ((u >> 16) & 1u)) >> 16;   // RNE
    return (unsigned short)r;
}
static __device__ __forceinline__ float bf2f(unsigned short s) {
    return __uint_as_float(((unsigned)s) << 16);
}
static __device__ __forceinline__ unsigned long long pack4(ushort4 s) {
    return (unsigned long long)s.x | ((unsigned long long)s.y << 16) |
           ((unsigned long long)s.z << 32) | ((unsigned long long)s.w << 48);
}

// ---------------------------------------------------------------------------
// fragment-ordered split-bf16 weight tables
// ---------------------------------------------------------------------------
__global__ void repack_bpk(const float* __restrict__ w, unsigned short* __restrict__ bpk) {
    int o = blockIdx.x * 256 + threadIdx.x;          // 131072 total
    int j = o & 7, lane = (o >> 3) & 63, h = (o >> 9) & 1;
    int nt = (o >> 10) & 3, ks = (o >> 12) & 1, l = o >> 13;
    int b = ks * 32 + (lane >> 4) * 8 + j;
    int c = nt * 16 + (lane & 15);
    float wv = w[(b * 64 + c) * 16 + l];
    unsigned short hb = f2bf(wv);
    bpk[o] = (h == 0) ? hb : f2bf(wv - bf2f(hb));
}

__global__ void repack_wlpk(const float* __restrict__ wl, unsigned short* __restrict__ wpk) {
    int o = blockIdx.x * 256 + threadIdx.x;          // 8192 total
    int j = o & 7, lane = (o >> 3) & 63, h = (o >> 9) & 1;
    int nt = (o >> 10) & 3, ks = o >> 12;
    int k = ks * 32 + (lane >> 4) * 8 + j;
    int c2 = nt * 16 + (lane & 15);
    float wv = wl[c2 * 64 + k];
    unsigned short hb = f2bf(wv);
    wpk[o] = (h == 0) ? hb : f2bf(wv - bf2f(hb));
}

// ---------------------------------------------------------------------------
// pool reference histogram: poolCnt[c] = #times perm row c is pooled.
// ---------------------------------------------------------------------------
__global__ __launch_bounds__(256) void pool_hist(const int* __restrict__ pcol,
                                                 int* __restrict__ poolCnt) {
    int i = blockIdx.x * 256 + threadIdx.x;
    if (i < NPERM_C) atomicAdd(&poolCnt[pcol[i]], 1);
}

// active-row compaction scan (flag = cnt!=0), deterministic.
__global__ __launch_bounds__(256) void pool_scan_local(const int* __restrict__ poolCnt,
                                                       int* __restrict__ poolRk,
                                                       int* __restrict__ bsum2) {
    __shared__ int ts[256];
    int b = blockIdx.x, t = threadIdx.x;
    int base = b * 2048 + t * 8;
    int v[8]; int s = 0;
#pragma unroll
    for (int i = 0; i < 8; ++i) {
        int idx = base + i;
        v[i] = (idx < NPERM_C) ? (poolCnt[idx] != 0) : 0;
        s += v[i];
    }
    ts[t] = s;
    __syncthreads();
    for (int ofs = 1; ofs < 256; ofs <<= 1) {
        int xv = (t >= ofs) ? ts[t - ofs] : 0;
        __syncthreads();
        ts[t] += xv;
        __syncthreads();
    }
    int run = ts[t] - s;
    if (t == 255) bsum2[b] = ts[255];
#pragma unroll
    for (int i = 0; i < 8; ++i) {
        int idx = base + i;
        if (idx < NPERM_C) poolRk[idx] = run;
        run += v[i];
    }
}

__global__ void pool_scan_top(int* __restrict__ bsum2) {
    __shared__ int ts[256];
    int t = threadIdx.x;
    int v = (t < NB2) ? bsum2[t] : 0;
    ts[t] = v;
    __syncthreads();
    for (int ofs = 1; ofs < 256; ofs <<= 1) {
        int xv = (t >= ofs) ? ts[t - ofs] : 0;
        __syncthreads();
        ts[t] += xv;
        __syncthreads();
    }
    if (t < NB2) bsum2[t] = ts[t] - v;
}

// finalize: poolRk[idx] := ((rank)<<1) | activeFlag ; nActB[0] = #active
__global__ __launch_bounds__(256) void pool_scan_add(const int* __restrict__ poolCnt,
                                                     int* __restrict__ poolRk,
                                                     const int* __restrict__ bsum2,
                                                     int* __restrict__ nActB) {
    int b = blockIdx.x, t = threadIdx.x;
    int add = bsum2[b];
    int base = b * 2048 + t * 8;
#pragma unroll
    for (int i = 0; i < 8; ++i) {
        int idx = base + i;
        if (idx < NPERM_C) {
            int flag = poolCnt[idx] != 0;
            int o = poolRk[idx] + add;
            poolRk[idx] = (o << 1) | flag;
            if (idx == NPERM_C - 1) nActB[0] = o + flag;
        }
    }
}

// ---------------------------------------------------------------------------
// slot histogram over ACTIVE rows, compact slot space, 4 entries/thread.
// ---------------------------------------------------------------------------
__global__ __launch_bounds__(256) void hist(const int* __restrict__ r1,
                                            const int* __restrict__ r2,
                                            const int* __restrict__ poolRk,
                                            int* __restrict__ cnt) {
    int i4 = (blockIdx.x * 256 + threadIdx.x) * 4;
    if (i4 >= 2 * P_C) return;
    const int* src = (i4 < P_C) ? (r1 + i4) : (r2 + (i4 - P_C));
    int4 r = *reinterpret_cast<const int4*>(src);
    int rr[4] = {r.x, r.y, r.z, r.w};
#pragma unroll
    for (int q = 0; q < 4; ++q) {
        int info = poolRk[rr[q] >> 4];
        if (info & 1) atomicAdd(&cnt[(info >> 1) * 16 + (rr[q] & 15)], 1);
    }
}

// big exclusive scan over 4M slot counts.
__global__ __launch_bounds__(256) void scan_local(const int* __restrict__ cnt,
                                                  int* __restrict__ off,
                                                  int* __restrict__ bsum) {
    __shared__ int ts[256];
    int b = blockIdx.x, t = threadIdx.x;
    int base = b * 2048 + t * 8;
    int v[8]; int s = 0;
#pragma unroll
    for (int i = 0; i < 8; ++i) {
        int idx = base + i;
        v[i] = (idx < P_C) ? cnt[idx] : 0;
        s += v[i];
    }
    ts[t] = s;
    __syncthreads();
    for (int ofs = 1; ofs < 256; ofs <<= 1) {
        int xv = (t >= ofs) ? ts[t - ofs] : 0;
        __syncthreads();
        ts[t] += xv;
        __syncthreads();
    }
    int run = ts[t] - s;
    if (t == 255) bsum[b] = ts[255];
#pragma unroll
    for (int i = 0; i < 8; ++i) {
        int idx = base + i;
        if (idx < P_C) off[idx] = run;
        run += v[i];
    }
}

__global__ void scan_top(int* __restrict__ bsum) {
    __shared__ int ts[256];
    int t = threadIdx.x;
    int base = t * 8;
    int v[8]; int s = 0;
#pragma unroll
    for (int i = 0; i < 8; ++i) {
        int idx = base + i;
        v[i] = (idx < NB1) ? bsum[idx] : 0;
        s += v[i];
    }
    ts[t] = s;
    __syncthreads();
    for (int ofs = 1; ofs < 256; ofs <<= 1) {
        int xv = (t >= ofs) ? ts[t - ofs] : 0;
        __syncthreads();
        ts[t] += xv;
        __syncthreads();
    }
    int run = ts[t] - s;
#pragma unroll
    for (int i = 0; i < 8; ++i) {
        int idx = base + i;
        if (idx < NB1) bsum[idx] = run;
        run += v[i];
    }
}

__global__ __launch_bounds__(256) void scan_add(int* __restrict__ off,
                                                const int* __restrict__ bsum,
                                                int* __restrict__ cur) {
    int b = blockIdx.x, t = threadIdx.x;
    int add = bsum[b];
    int base = b * 2048 + t * 8;
#pragma unroll
    for (int i = 0; i < 8; ++i) {
        int idx = base + i;
        if (idx < P_C) {
            int o = off[idx] + add;
            if (idx == P_C - 1) off[P_C] = o + cur[idx];  // cur still holds count
            off[idx] = o;
            cur[idx] = o;
        }
    }
}

// ---------------------------------------------------------------------------
// scatter active entries to sorted position, 2 entries/thread, nt stores.
// ---------------------------------------------------------------------------
__global__ __launch_bounds__(256) void scat(
        const int* __restrict__ r1, const int* __restrict__ c1, const float* __restrict__ v1,
        const int* __restrict__ r2, const int* __restrict__ c2, const float* __restrict__ v2,
        const int* __restrict__ poolRk,
        int* __restrict__ cur, unsigned long long* __restrict__ suv) {
    int i2 = (blockIdx.x * 256 + threadIdx.x) * 2;
    if (i2 >= 2 * P_C) return;
    const int* rr; const int* cc; const float* vv; unsigned srcbit; int base;
    if (i2 < P_C) { rr = r1; cc = c1; vv = v1; srcbit = 0u; base = i2; }
    else          { rr = r2; cc = c2; vv = v2; srcbit = 0x100000u; base = i2 - P_C; }
    int2 r = *reinterpret_cast<const int2*>(rr + base);
    int2 c = *reinterpret_cast<const int2*>(cc + base);
    float2 v = *reinterpret_cast<const float2*>(vv + base);
    {
        int info = poolRk[r.x >> 4];
        if (info & 1) {
            int pos = atomicAdd(&cur[(info >> 1) * 16 + (r.x & 15)], 1);
            unsigned long long e = (unsigned long long)((unsigned)c.x | srcbit) |
                                   ((unsigned long long)__float_as_uint(v.x) << 32);
            __builtin_nontemporal_store(e, suv + pos);
        }
    }
    {
        int info = poolRk[r.y >> 4];
        if (info & 1) {
            int pos = atomicAdd(&cur[(info >> 1) * 16 + (r.y & 15)], 1);
            unsigned long long e = (unsigned long long)((unsigned)c.y | srcbit) |
                                   ((unsigned long long)__float_as_uint(v.y) << 32);
            __builtin_nontemporal_store(e, suv + pos);
        }
    }
}

// ---------------------------------------------------------------------------
// CSR gather (round-5 structure, compact pOff). float4-per-lane:
// 16-lane group owns 2 chains; wave = 8 slots; block = 2 compact rows.
// nt loads for suv (stream-once), nt stores for planes (write-once).
// ---------------------------------------------------------------------------
__global__ __launch_bounds__(256) void gather_nfeat(
        const unsigned long long* __restrict__ suv, const int* __restrict__ pOff,
        const float* __restrict__ x, const float* __restrict__ efeat,
        const float* __restrict__ degs, const int* __restrict__ nActB,
        unsigned short* __restrict__ nfH, unsigned short* __restrict__ nfL,
        float* __restrict__ degD, int row0, int rows) {
    int nAct = nActB[0];
    int t = threadIdx.x;
    int w = t >> 6, lane = t & 63;
    int g = lane >> 4, t16 = lane & 15;
    int cr = row0 + blockIdx.x * 2 + (w >> 1);
    int rend = row0 + rows; if (rend > nAct) rend = nAct;
    if (cr >= rend) return;                 // wave-uniform
    int posA = (w & 1) * 8 + g * 2;
    int posB = posA + 1;
    int sA = cr * 16 + posA;
    int iA = pOff[sA];
    int eA = pOff[sA + 1];
    int iB = eA;
    int eB = pOff[sA + 2];
    bool needA = (posA == 0) || (posA == 10);
    bool needB = (posB == 5) || (posB == 15);
    float4 aA = {0.f, 0.f, 0.f, 0.f}, aB = {0.f, 0.f, 0.f, 0.f};
    float dA = 0.f, dB = 0.f;
    while ((iA < eA) || (iB < eB)) {
        bool hA = iA < eA, hB = iB < eB;
        unsigned long long kvA, kvB;
        if (hA) kvA = __builtin_nontemporal_load(suv + iA);
        if (hB) kvB = __builtin_nontemporal_load(suv + iB);
        if (hA) {
            unsigned k = (unsigned)kvA; float v = __uint_as_float((unsigned)(kvA >> 32));
            const float* f = (k & 0x100000u) ? efeat : x;
            float4 fv = *reinterpret_cast<const float4*>(
                f + (size_t)(k & 0xFFFFFu) * 64 + t16 * 4);
            aA.x = fmaf(v, fv.x, aA.x); aA.y = fmaf(v, fv.y, aA.y);
            aA.z = fmaf(v, fv.z, aA.z); aA.w = fmaf(v, fv.w, aA.w);
            if (needA && !(k & 0x100000u)) dA = fmaf(v, degs[k & 0xFFFFFu], dA);
            ++iA;
        }
        if (hB) {
            unsigned k = (unsigned)kvB; float v = __uint_as_float((unsigned)(kvB >> 32));
            const float* f = (k & 0x100000u) ? efeat : x;
            float4 fv = *reinterpret_cast<const float4*>(
                f + (size_t)(k & 0xFFFFFu) * 64 + t16 * 4);
            aB.x = fmaf(v, fv.x, aB.x); aB.y = fmaf(v, fv.y, aB.y);
            aB.z = fmaf(v, fv.z, aB.z); aB.w = fmaf(v, fv.w, aB.w);
            if (needB && !(k & 0x100000u)) dB = fmaf(v, degs[k & 0xFFFFFu], dB);
            ++iB;
        }
    }
    size_t o = ((size_t)(cr - row0) * 16 + posA) * 64 + t16 * 4;
    ushort4 h4, l4;
    h4.x = f2bf(aA.x); l4.x = f2bf(aA.x - bf2f(h4.x));
    h4.y = f2bf(aA.y); l4.y = f2bf(aA.y - bf2f(h4.y));
    h4.z = f2bf(aA.z); l4.z = f2bf(aA.z - bf2f(h4.z));
    h4.w = f2bf(aA.w); l4.w = f2bf(aA.w - bf2f(h4.w));
    __builtin_nontemporal_store(pack4(h4), reinterpret_cast<unsigned long long*>(nfH + o));
    __builtin_nontemporal_store(pack4(l4), reinterpret_cast<unsigned long long*>(nfL + o));
    h4.x = f2bf(aB.x); l4.x = f2bf(aB.x - bf2f(h4.x));
    h4.y = f2bf(aB.y); l4.y = f2bf(aB.y - bf2f(h4.y));
    h4.z = f2bf(aB.z); l4.z = f2bf(aB.z - bf2f(h4.z));
    h4.w = f2bf(aB.w); l4.w = f2bf(aB.w - bf2f(h4.w));
    __builtin_nontemporal_store(pack4(h4), reinterpret_cast<unsigned long long*>(nfH + o + 64));
    __builtin_nontemporal_store(pack4(l4), reinterpret_cast<unsigned long long*>(nfL + o + 64));
    if (t16 == 0) {
        if (needA) degD[(size_t)cr * 4 + posA / 5] = dA;
        if (needB) degD[(size_t)cr * 4 + posB / 5] = dB;
    }
}

// ---------------------------------------------------------------------------
// degree-gate MLP over compact rows [r0, min(r0+rows, nAct)).
// ---------------------------------------------------------------------------
__global__ __launch_bounds__(256) void dg_gemm(
        const float* __restrict__ degD,
        const float* __restrict__ W0, const float* __restrict__ b0,
        const float* __restrict__ W1, const float* __restrict__ b1,
        const int* __restrict__ nActB,
        float* __restrict__ dgb, int r0, int rows) {
    __shared__ float hidT[128][68];   // [h][r]
    __shared__ float w1T[128][68];    // [h][c]
    __shared__ float dloc[64][4];
    __shared__ float w0s[128][5];
    int nAct = nActB[0];
    int rend = r0 + rows; if (rend > nAct) rend = nAct;
    int t = threadIdx.x;
    int m0 = r0 + blockIdx.x * 64;
    if (m0 >= rend) return;

    {
        int r = t >> 2, j = t & 3;
        int gr = m0 + r; if (gr >= rend) gr = rend - 1;
        dloc[r][j] = degD[(size_t)gr * 4 + j];
    }
    if (t < 128) {
        w0s[t][0] = W0[t * 4 + 0]; w0s[t][1] = W0[t * 4 + 1];
        w0s[t][2] = W0[t * 4 + 2]; w0s[t][3] = W0[t * 4 + 3];
        w0s[t][4] = b0[t];
    }
    for (int s = 0; s < 32; ++s) {
        int idx = t + s * 256;
        w1T[idx & 127][idx >> 7] = W1[idx];
    }
    __syncthreads();
    for (int s = 0; s < 32; ++s) {
        int idx = t + s * 256;
        int h = idx & 127, r = idx >> 7;
        float v = w0s[h][4] + dloc[r][0] * w0s[h][0] + dloc[r][1] * w0s[h][1]
                            + dloc[r][2] * w0s[h][2] + dloc[r][3] * w0s[h][3];
        hidT[h][r] = fmaxf(v, 0.f);
    }
    __syncthreads();

    int tm = t >> 4, tn = t & 15;
    float acc[4][4] = {};
#pragma unroll 8
    for (int k = 0; k < 128; ++k) {
        float4 a = *reinterpret_cast<const float4*>(&hidT[k][tm * 4]);
        float4 b = *reinterpret_cast<const float4*>(&w1T[k][tn * 4]);
        acc[0][0] = fmaf(a.x, b.x, acc[0][0]); acc[0][1] = fmaf(a.x, b.y, acc[0][1]);
        acc[0][2] = fmaf(a.x, b.z, acc[0][2]); acc[0][3] = fmaf(a.x, b.w, acc[0][3]);
        acc[1][0] = fmaf(a.y, b.x, acc[1][0]); acc[1][1] = fmaf(a.y, b.y, acc[1][1]);
        acc[1][2] = fmaf(a.y, b.z, acc[1][2]); acc[1][3] = fmaf(a.y, b.w, acc[1][3]);
        acc[2][0] = fmaf(a.z, b.x, acc[2][0]); acc[2][1] = fmaf(a.z, b.y, acc[2][1]);
        acc[2][2] = fmaf(a.z, b.z, acc[2][2]); acc[2][3] = fmaf(a.z, b.w, acc[2][3]);
        acc[3][0] = fmaf(a.w, b.x, acc[3][0]); acc[3][1] = fmaf(a.w, b.y, acc[3][1]);
        acc[3][2] = fmaf(a.w, b.z, acc[3][2]); acc[3][3] = fmaf(a.w, b.w, acc[3][3]);
    }
    float bb[4] = {b1[tn * 4 + 0], b1[tn * 4 + 1], b1[tn * 4 + 2], b1[tn * 4 + 3]};
#pragma unroll
    for (int i = 0; i < 4; ++i) {
        int grow = m0 + tm * 4 + i;
        if (grow < rend) {
            float4 o = {acc[i][0] + bb[0], acc[i][1] + bb[1],
                        acc[i][2] + bb[2], acc[i][3] + bb[3]};
            *reinterpret_cast<float4*>(&dgb[(size_t)grow * 64 + tn * 4]) = o;
        }
    }
}

// ---------------------------------------------------------------------------
// MFMA einsum + epilogue (split-bf16, 3 products) over compact rows.
// ---------------------------------------------------------------------------
__global__ __launch_bounds__(256) void gemm_mfma(
        const unsigned short* __restrict__ nfH, const unsigned short* __restrict__ nfL,
        const unsigned short* __restrict__ Bpk, const unsigned short* __restrict__ Wlpk,
        const float* __restrict__ bias, const float* __restrict__ bl,
        const float* __restrict__ dgb, const int* __restrict__ nActB,
        float* __restrict__ outb, int r0, int rows) {
    __shared__ unsigned short Hh[128][72];
    __shared__ unsigned short Hl[128][72];
    int nAct = nActB[0];
    int rowsEff = rows; if (r0 + rowsEff > nAct) rowsEff = nAct - r0;
    int t = threadIdx.x, lane = t & 63, w = t >> 6;
    int m0 = blockIdx.x * 128;
    if (m0 >= rowsEff) return;
    int r16 = lane & 15, kg = lane >> 4;

    f32x4 acc[2][4];
#pragma unroll
    for (int i = 0; i < 2; ++i)
#pragma unroll
        for (int j = 0; j < 4; ++j) acc[i][j] = (f32x4){0.f, 0.f, 0.f, 0.f};

    for (int l = 0; l < 16; ++l) {
#pragma unroll
        for (int ks = 0; ks < 2; ++ks) {
            bf16x8 ah[2], al[2];
#pragma unroll
            for (int mt = 0; mt < 2; ++mt) {
                int lr = m0 + w * 32 + mt * 16 + r16;
                if (lr >= rowsEff) lr = rowsEff - 1;
                size_t off = ((size_t)lr * 16 + l) * 64 + ks * 32 + kg * 8;
                ah[mt] = *reinterpret_cast<const bf16x8*>(nfH + off);
                al[mt] = *reinterpret_cast<const bf16x8*>(nfL + off);
            }
#pragma unroll
            for (int nt = 0; nt < 4; ++nt) {
                const unsigned short* bb =
                    Bpk + (size_t)(((l * 2 + ks) * 4 + nt) * 2) * 512 + lane * 8;
                bf16x8 bh = *reinterpret_cast<const bf16x8*>(bb);
                bf16x8 blo = *reinterpret_cast<const bf16x8*>(bb + 512);
#pragma unroll
                for (int mt = 0; mt < 2; ++mt) {
                    acc[mt][nt] = __builtin_amdgcn_mfma_f32_16x16x32_bf16(ah[mt], bh,  acc[mt][nt], 0, 0, 0);
                    acc[mt][nt] = __builtin_amdgcn_mfma_f32_16x16x32_bf16(ah[mt], blo, acc[mt][nt], 0, 0, 0);
                    acc[mt][nt] = __builtin_amdgcn_mfma_f32_16x16x32_bf16(al[mt], bh,  acc[mt][nt], 0, 0, 0);
                }
            }
        }
    }

    // epilogue 1: h = relu(acc + bias) -> split-bf16 LDS planes
#pragma unroll
    for (int mt = 0; mt < 2; ++mt)
#pragma unroll
        for (int nt = 0; nt < 4; ++nt) {
            int col = nt * 16 + r16;
            float bv = bias[col];
#pragma unroll
            for (int reg = 0; reg < 4; ++reg) {
                int rl = w * 32 + mt * 16 + kg * 4 + reg;
                float h = fmaxf(acc[mt][nt][reg] + bv, 0.f);
                unsigned short hb = f2bf(h);
                Hh[rl][col] = hb;
                Hl[rl][col] = f2bf(h - bf2f(hb));
            }
        }
    __syncthreads();

    f32x4 acc2[2][4];
#pragma unroll
    for (int i = 0; i < 2; ++i)
#pragma unroll
        for (int j = 0; j < 4; ++j) acc2[i][j] = (f32x4){0.f, 0.f, 0.f, 0.f};

#pragma unroll
    for (int ks = 0; ks < 2; ++ks) {
        bf16x8 ah[2], al[2];
#pragma unroll
        for (int mt = 0; mt < 2; ++mt) {
            int rl = w * 32 + mt * 16 + r16;
            ah[mt] = *reinterpret_cast<const bf16x8*>(&Hh[rl][ks * 32 + kg * 8]);
            al[mt] = *reinterpret_cast<const bf16x8*>(&Hl[rl][ks * 32 + kg * 8]);
        }
#pragma unroll
        for (int nt = 0; nt < 4; ++nt) {
            const unsigned short* wb =
                Wlpk + (size_t)(((ks * 4 + nt) * 2)) * 512 + lane * 8;
            bf16x8 bh = *reinterpret_cast<const bf16x8*>(wb);
            bf16x8 blo = *reinterpret_cast<const bf16x8*>(wb + 512);
#pragma unroll
            for (int mt = 0; mt < 2; ++mt) {
                acc2[mt][nt] = __builtin_amdgcn_mfma_f32_16x16x32_bf16(ah[mt], bh,  acc2[mt][nt], 0, 0, 0);
                acc2[mt][nt] = __builtin_amdgcn_mfma_f32_16x16x32_bf16(ah[mt], blo, acc2[mt][nt], 0, 0, 0);
                acc2[mt][nt] = __builtin_amdgcn_mfma_f32_16x16x32_bf16(al[mt], bh,  acc2[mt][nt], 0, 0, 0);
            }
        }
    }

    // epilogue 2: out = (h2 + bl) * dg
#pragma unroll
    for (int mt = 0; mt < 2; ++mt)
#pragma unroll
        for (int nt = 0; nt < 4; ++nt) {
            int col = nt * 16 + r16;
            float bv = bl[col];
#pragma unroll
            for (int reg = 0; reg < 4; ++reg) {
                int rl = w * 32 + mt * 16 + kg * 4 + reg;
                if (m0 + rl < rowsEff) {
                    size_t idx = (size_t)(r0 + m0 + rl) * 64 + col;
                    outb[idx] = (acc2[mt][nt][reg] + bv) * dgb[idx];
                }
            }
        }
}

// ---------------------------------------------------------------------------
// pooling scatter: rank-translated compact read, one wave per nnz.
// ---------------------------------------------------------------------------
__global__ __launch_bounds__(256) void pool_scatter(
        const int* __restrict__ prow, const int* __restrict__ pcol,
        const float* __restrict__ pval, const int* __restrict__ poolRk,
        const float* __restrict__ outb, float* __restrict__ out) {
    int t = blockIdx.x * 256 + threadIdx.x;
    int i = t >> 6, d = t & 63;
    if (i >= NPERM_C) return;
    int r = prow[i], c = pcol[i];
    float v = pval[i];
    int cr = poolRk[c] >> 1;
    atomicAdd(&out[(size_t)r * 64 + d], v * outb[(size_t)cr * 64 + d]);
}

extern "C" void kernel_launch(void* const* d_in, const int* in_sizes, int n_in,
                              void* d_out, int out_size, void* d_ws, size_t ws_size,
                              hipStream_t stream) {
    const float* x       = (const float*)d_in[0];
    const float* efeat   = (const float*)d_in[1];
    const float* degs    = (const float*)d_in[2];
    const int*   n2p_row = (const int*)d_in[3];
    const int*   n2p_col = (const int*)d_in[4];
    const float* n2p_val = (const float*)d_in[5];
    const int*   e2p_row = (const int*)d_in[6];
    const int*   e2p_col = (const int*)d_in[7];
    const float* e2p_val = (const float*)d_in[8];
    const int*   pool_row = (const int*)d_in[9];
    const int*   pool_col = (const int*)d_in[10];
    const float* pool_val = (const float*)d_in[11];
    const float* weights = (const float*)d_in[12];
    const float* bias    = (const float*)d_in[13];
    const float* W0      = (const float*)d_in[14];
    const float* b0      = (const float*)d_in[15];
    const float* W1      = (const float*)d_in[16];
    const float* b1      = (const float*)d_in[17];
    const float* Wl      = (const float*)d_in[18];
    const float* bl      = (const float*)d_in[19];
    float* out = (float*)d_out;

    // workspace layout (4B elems)
    unsigned long long* suv = (unsigned long long*)d_ws;   // 16,000,000 (8M x 8B)
    int*   pOff     = (int*)(suv + 8000000);           //  4,000,064
    int*   pCur     = pOff + 4000064;                  //  4,000,000
    int*   bsum     = pCur + 4000000;                  //      2,048
    int*   poolCnt  = bsum + 2048;                     //    250,000
    int*   poolRk   = poolCnt + 250000;                //    250,000
    int*   bsum2    = poolRk + 250000;                 //        256
    int*   nActB    = bsum2 + 256;                     //         16
    unsigned short* Bpk  = (unsigned short*)(nActB + 16);   // 131072 us = 65536
    unsigned short* Wlpk = Bpk + 131072;                    //   8192 us =  4096
    float* degD = (float*)(Wlpk + 8192);               //  1,000,000
    float* dgb  = degD + 1000000;                      // 16,000,000
    float* outb = dgb;                                 // alias (same-idx RAW)
    unsigned short* nfH = (unsigned short*)(dgb + 16000000);

    const long long base_elems = 16000000LL + 4000064 + 4000000 + 2048 +
                                 250000 * 2 + 256 + 16 + 65536 + 4096 +
                                 1000000 + 16000000;   // 41,572,016
    long long availf = (long long)(ws_size / 4) - base_elems;
    long long chl = availf / 1024;   // per row: 2 planes * 16*64 * 2B = 4 KB
    if (chl > NPERM_C) chl = NPERM_C;
    int CH = (int)(chl & ~127LL);
    if (CH < 128) {
        hipMemsetAsync(d_out, 0, (size_t)out_size * 4, stream);
        return;
    }
    unsigned short* nfL = nfH + (size_t)CH * 1024;

    hipMemsetAsync(pCur, 0, (size_t)P_C * 4, stream);
    hipMemsetAsync(poolCnt, 0, (size_t)NPERM_C * 4, stream);
    hipMemsetAsync(out, 0, (size_t)G_C * 64 * 4, stream);

    repack_bpk<<<512, 256, 0, stream>>>(weights, Bpk);
    repack_wlpk<<<32, 256, 0, stream>>>(Wl, Wlpk);

    pool_hist<<<(NPERM_C + 255) / 256, 256, 0, stream>>>(pool_col, poolCnt);
    pool_scan_local<<<NB2, 256, 0, stream>>>(poolCnt, poolRk, bsum2);
    pool_scan_top<<<1, 256, 0, stream>>>(bsum2);
    pool_scan_add<<<NB2, 256, 0, stream>>>(poolCnt, poolRk, bsum2, nActB);

    hist<<<7813, 256, 0, stream>>>(n2p_row, e2p_row, poolRk, pCur);
    scan_local<<<NB1, 256, 0, stream>>>(pCur, pOff, bsum);
    scan_top<<<1, 256, 0, stream>>>(bsum);
    scan_add<<<NB1, 256, 0, stream>>>(pOff, bsum, pCur);
    scat<<<15625, 256, 0, stream>>>(n2p_row, n2p_col, n2p_val,
                                    e2p_row, e2p_col, e2p_val,
                                    poolRk, pCur, suv);

    for (int c0 = 0; c0 < NPERM_C; c0 += CH) {
        int rows = NPERM_C - c0; if (rows > CH) rows = CH;
        gather_nfeat<<<(rows + 1) / 2, 256, 0, stream>>>(
            suv, pOff, x, efeat, degs, nActB, nfH, nfL, degD, c0, rows);
        dg_gemm<<<(rows + 63) / 64, 256, 0, stream>>>(
            degD, W0, b0, W1, b1, nActB, dgb, c0, rows);
        gemm_mfma<<<(rows + 127) / 128, 256, 0, stream>>>(
            nfH, nfL, Bpk, Wlpk, bias, bl, dgb, nActB, outb, c0, rows);
    }

    pool_scatter<<<62500, 256, 0, stream>>>(pool_row, pool_col, pool_val,
                                            poolRk, outb, out);
}